// Round 7
// baseline (228.606 us; speedup 1.0000x reference)
//
#include <hip/hip_runtime.h>
#include <hip/hip_bf16.h>
#include <stdint.h>

typedef __attribute__((ext_vector_type(4))) float f32x4;
typedef __attribute__((ext_vector_type(8))) short s16x8;

__device__ __forceinline__ unsigned int f2bf_u(float x) {
  union { float f; unsigned int u; } v; v.f = x;
  return (v.u + 0x7FFFu + ((v.u >> 16) & 1u)) >> 16;   // RNE
}
// Packed f32->bf16 RNE via compiler intrinsic: emits v_cvt_pk_bf16_f32
// (1 instr; replaces the ~11-op manual RNE pair). RNE = bit-identical to
// f2bf_u on finite inputs.
__device__ __forceinline__ unsigned int pack_bf2(float lo, float hi) {
  float2 f2; f2.x = lo; f2.y = hi;
  union { __hip_bfloat162 h2; unsigned int u; } v;
  v.h2 = __float22bfloat162_rn(f2);
  return v.u;
}
__device__ __forceinline__ float bflo(unsigned int w) { return __uint_as_float(w << 16); }
__device__ __forceinline__ float bfhi(unsigned int w) { return __uint_as_float(w & 0xFFFF0000u); }

union FragU { uint4 u; s16x8 s; };

// Convert W_qk (16384 f32) and W_v (16384 f32) to bf16 in workspace.
__global__ void __launch_bounds__(256) prep_weights(const float* __restrict__ Wqk,
                                                    const float* __restrict__ Wv,
                                                    uint16_t* __restrict__ wsqk,
                                                    uint16_t* __restrict__ wsv) {
  int i = blockIdx.x * 256 + threadIdx.x;
  if (i < 16384) {
    wsqk[i] = (uint16_t)f2bf_u(Wqk[i]);
  } else if (i < 32768) {
    int j = i - 16384;
    wsv[j] = (uint16_t)f2bf_u(Wv[j]);
  }
}

// R6 structure (proven best, attn ~74us) with ONE isolated change: pack_bf2
// now uses the HW packed convert. This is both an optimization (~40% fewer
// VALU/thread) and the discriminating A/B between "VALU-issue on the barrier
// chain" (predict -8..-12us) and "latency convoy" (predict ~0).
__global__ void __launch_bounds__(256, 6) attn_kernel(
    const float* __restrict__ X,          // (16,128,1024,16) f32
    const float* __restrict__ bqk,        // (128) f32
    const float* __restrict__ bv,         // (128) f32
    const unsigned int* __restrict__ wqk, // 128x128 bf16 as 8192 words
    const unsigned int* __restrict__ wv,  // 128x128 bf16 as 8192 words
    float* __restrict__ out)              // (16,1024,128) f32
{
  __shared__ unsigned int sXt[64 * 66];   // Xt[j=n*16+k][c-pair], stride 66 words
  __shared__ unsigned int sPt[64 * 34];   // P^T half: [j][o-pair 0..31], stride 34
  __shared__ unsigned int sY[4 * 68];     // y_n[c-pair] bf16
  __shared__ float sa[4][16];
  __shared__ float sS[4];

  const int t    = threadIdx.x;
  const int lane = t & 63;
  const int w    = t >> 6;      // wave 0..3
  const int nn   = lane & 15;
  const int quad = lane >> 4;

  const int blk = blockIdx.x;
  const int b   = blk >> 8;
  const int n0  = (blk & 255) << 2;

  // ---- Stage A: coalesced float4 + in-register 4x4 quad transpose -> sXt ----
  {
    const int j4 = nn;
    const int q  = quad;
    const float* Xg = X + (size_t)b * (128 * 1024 * 16) + (size_t)n0 * 16;
    #pragma unroll
    for (int it = 0; it < 8; ++it) {
      const int cbase = it * 16 + w * 4;      // multiple of 4
      const int c = cbase + q;
      float4 V = *reinterpret_cast<const float4*>(Xg + (size_t)c * 16384 + j4 * 4);
      {
        const bool Q0 = (q >> 1) == 0;
        float a  = Q0 ? V.z : V.x;
        float bb = Q0 ? V.w : V.y;
        a  = __shfl_xor(a, 32);
        bb = __shfl_xor(bb, 32);
        if (Q0) { V.z = a; V.w = bb; } else { V.x = a; V.y = bb; }
      }
      {
        const bool q0 = (q & 1) == 0;
        float a  = q0 ? V.y : V.x;
        float bb = q0 ? V.w : V.z;
        a  = __shfl_xor(a, 16);
        bb = __shfl_xor(bb, 16);
        if (q0) { V.y = a; V.w = bb; } else { V.x = a; V.z = bb; }
      }
      const int j = 4 * j4 + q;
      uint2 pk;
      pk.x = pack_bf2(V.x, V.y);
      pk.y = pack_bf2(V.z, V.w);
      *reinterpret_cast<uint2*>(&sXt[j * 66 + (cbase >> 1)]) = pk;
    }
  }
  __syncthreads();

  f32x4 e; e[0] = 0.f; e[1] = 0.f; e[2] = 0.f; e[3] = 0.f;

  #pragma unroll
  for (int h = 0; h < 2; ++h) {
    // ---- Stage 1 half h: 64 o's (Q 32h.., K 64+32h..) split over 4 waves ----
    const int O       = (w < 2) ? (32 * h + 16 * w) : (64 + 32 * h + 16 * (w - 2));
    const int colbase = (w < 2) ? (8 * w)           : (16 + 8 * (w - 2));
    f32x4 acc[4];
    {
      const float4 bq = *reinterpret_cast<const float4*>(bqk + O + quad * 4);
      #pragma unroll
      for (int tt = 0; tt < 4; ++tt) {
        acc[tt][0] = bq.x; acc[tt][1] = bq.y; acc[tt][2] = bq.z; acc[tt][3] = bq.w;
      }
    }
    #pragma unroll
    for (int ks = 0; ks < 4; ++ks) {
      FragU af, bf[4];
      af.u = *reinterpret_cast<const uint4*>(wqk + (O + nn) * 64 + ks * 16 + quad * 4);
      #pragma unroll
      for (int tt = 0; tt < 4; ++tt)
        bf[tt].u = *reinterpret_cast<const uint4*>(&sXt[(tt * 16 + nn) * 66 + ks * 16 + quad * 4]);
      #pragma unroll
      for (int tt = 0; tt < 4; ++tt)
        acc[tt] = __builtin_amdgcn_mfma_f32_16x16x32_bf16(af.s, bf[tt].s, acc[tt], 0, 0, 0);
    }
    // Epilogue: Pt[j][colbase + quad*2 + {0,1}] (pair parity trick)
    #pragma unroll
    for (int tt = 0; tt < 4; ++tt) {
      const int j = tt * 16 + nn;
      const unsigned int pw0 = pack_bf2(acc[tt][0], acc[tt][1]);
      const unsigned int pw1 = pack_bf2(acc[tt][2], acc[tt][3]);
      #pragma unroll
      for (int s = 0; s < 2; ++s) {
        const int rp = (nn + s) & 1;
        sPt[j * 34 + colbase + quad * 2 + rp] = rp ? pw1 : pw0;
      }
    }
    __syncthreads();   // Pt half complete -> all waves may read

    // ---- Stage 2 half h: E += Q_h^T K_h (wave w -> n=w) ----
    {
      const int row = (w * 16 + nn) * 34;
      FragU qf, kf;
      const uint2 qlo = *reinterpret_cast<const uint2*>(&sPt[row + quad * 4]);
      const uint2 qhi = *reinterpret_cast<const uint2*>(&sPt[row + quad * 4 + 2]);
      const uint2 klo = *reinterpret_cast<const uint2*>(&sPt[row + 16 + quad * 4]);
      const uint2 khi = *reinterpret_cast<const uint2*>(&sPt[row + 16 + quad * 4 + 2]);
      qf.u.x = qlo.x; qf.u.y = qlo.y; qf.u.z = qhi.x; qf.u.w = qhi.y;
      kf.u.x = klo.x; kf.u.y = klo.y; kf.u.z = khi.x; kf.u.w = khi.y;
      e = __builtin_amdgcn_mfma_f32_16x16x32_bf16(qf.s, kf.s, e, 0, 0, 0);
    }
    if (h == 0) __syncthreads();   // protect Pt from half-1 overwrite
  }

  // ---- softmax over k (cols = nn), rows q = quad*4 + rr ----
  {
    float p[4], sm[4];
    #pragma unroll
    for (int rr = 0; rr < 4; ++rr) {
      float l = e[rr] * 0.125f;                        // /sqrt(64)
      float mx = l;
      mx = fmaxf(mx, __shfl_xor(mx, 1));
      mx = fmaxf(mx, __shfl_xor(mx, 2));
      mx = fmaxf(mx, __shfl_xor(mx, 4));
      mx = fmaxf(mx, __shfl_xor(mx, 8));
      float pe = __expf(l - mx);
      float ss = pe;
      ss += __shfl_xor(ss, 1);
      ss += __shfl_xor(ss, 2);
      ss += __shfl_xor(ss, 4);
      ss += __shfl_xor(ss, 8);
      p[rr] = pe; sm[rr] = ss;
    }
    if (nn == 0) {
      #pragma unroll
      for (int rr = 0; rr < 4; ++rr) sa[w][quad * 4 + rr] = p[rr] / sm[rr];
    }
  }

  // ---- Stage Y: y_n = X_n a_n -> sY row w (bf16); S_n (wave-local) ----
  {
    float a[16];
    float S = 0.f;
    #pragma unroll
    for (int k = 0; k < 16; ++k) { a[k] = sa[w][k]; S += a[k]; }
    float y0 = 0.f, y1 = 0.f;
    #pragma unroll
    for (int k = 0; k < 16; ++k) {
      const unsigned int xw = sXt[(w * 16 + k) * 66 + lane];   // stride-1
      y0 += a[k] * bflo(xw);
      y1 += a[k] * bfhi(xw);
    }
    sY[w * 68 + lane] = pack_bf2(y0, y1);
    if (lane == 0) sS[w] = S;
  }
  __syncthreads();   // sY/sS cross-wave -> stage 3

  // ---- Stage 3: Out = Wv @ Y + bv * S ----
  {
    #pragma unroll
    for (int i = 0; i < 2; ++i) {
      const int ct = w * 2 + i;   // c-out tile, 8 tiles over 4 waves
      f32x4 z; z[0] = 0.f; z[1] = 0.f; z[2] = 0.f; z[3] = 0.f;
      #pragma unroll
      for (int ks = 0; ks < 4; ++ks) {
        FragU av, by;
        av.u = *reinterpret_cast<const uint4*>(wv + (ct * 16 + nn) * 64 + ks * 16 + quad * 4);
        uint4 tmp; tmp.x = 0u; tmp.y = 0u; tmp.z = 0u; tmp.w = 0u;
        if (nn < 4) tmp = *reinterpret_cast<const uint4*>(&sY[nn * 68 + ks * 16 + quad * 4]);
        by.u = tmp;
        z = __builtin_amdgcn_mfma_f32_16x16x32_bf16(av.s, by.s, z, 0, 0, 0);
      }
      if (nn < 4) {
        const float4 bvv = *reinterpret_cast<const float4*>(bv + ct * 16 + quad * 4);
        const float S = sS[nn];
        float4 o4;
        o4.x = z[0] + bvv.x * S;
        o4.y = z[1] + bvv.y * S;
        o4.z = z[2] + bvv.z * S;
        o4.w = z[3] + bvv.w * S;
        *reinterpret_cast<float4*>(out + (size_t)(b * 1024 + n0 + nn) * 128 + ct * 16 + quad * 4) = o4;
      }
    }
  }
}

extern "C" void kernel_launch(void* const* d_in, const int* in_sizes, int n_in,
                              void* d_out, int out_size, void* d_ws, size_t ws_size,
                              hipStream_t stream) {
  (void)in_sizes; (void)n_in; (void)out_size; (void)ws_size;
  const float* X   = (const float*)d_in[0];
  const float* Wqk = (const float*)d_in[1];
  const float* bqk = (const float*)d_in[2];
  const float* Wv  = (const float*)d_in[3];
  const float* bv  = (const float*)d_in[4];
  // d_in[5] = qk_dim (=64), compile-time constant here.

  uint16_t* wsqk = (uint16_t*)d_ws;           // 32 KB
  uint16_t* wsv  = wsqk + 16384;              // 32 KB

  prep_weights<<<128, 256, 0, stream>>>(Wqk, Wv, wsqk, wsv);
  attn_kernel<<<4096, 256, 0, stream>>>(X, bqk, bv,
                                        (const unsigned int*)wsqk,
                                        (const unsigned int*)wsv,
                                        (float*)d_out);
}

// Round 9
// 226.870 us; speedup vs baseline: 1.0077x; 1.0077x over previous
//
#include <hip/hip_runtime.h>
#include <hip/hip_bf16.h>
#include <stdint.h>

typedef __attribute__((ext_vector_type(4))) float f32x4;
typedef __attribute__((ext_vector_type(8))) short s16x8;

__device__ __forceinline__ unsigned int f2bf_u(float x) {
  union { float f; unsigned int u; } v; v.f = x;
  return (v.u + 0x7FFFu + ((v.u >> 16) & 1u)) >> 16;   // RNE
}
// Packed f32->bf16 RNE via compiler intrinsic (v_cvt_pk_bf16_f32).
__device__ __forceinline__ unsigned int pack_bf2(float lo, float hi) {
  float2 f2; f2.x = lo; f2.y = hi;
  union { __hip_bfloat162 h2; unsigned int u; } v;
  v.h2 = __float22bfloat162_rn(f2);
  return v.u;
}
__device__ __forceinline__ float bflo(unsigned int w) { return __uint_as_float(w << 16); }
__device__ __forceinline__ float bfhi(unsigned int w) { return __uint_as_float(w & 0xFFFF0000u); }

union FragU { uint4 u; s16x8 s; };

// Convert W_qk (16384 f32) and W_v (16384 f32) to bf16 in workspace.
__global__ void __launch_bounds__(256) prep_weights(const float* __restrict__ Wqk,
                                                    const float* __restrict__ Wv,
                                                    uint16_t* __restrict__ wsqk,
                                                    uint16_t* __restrict__ wsv) {
  int i = blockIdx.x * 256 + threadIdx.x;
  if (i < 16384) {
    wsqk[i] = (uint16_t)f2bf_u(Wqk[i]);
  } else if (i < 32768) {
    int j = i - 16384;
    wsv[j] = (uint16_t)f2bf_u(Wv[j]);
  }
}

// R6/R7 structure with two DS-pipe cuts (resubmit of R8 — infra failure,
// no measurement obtained):
//  (1) stage 1 unified: bf X-fragments loaded ONCE, feed both o-halves'
//      MFMAs (acc[2][4] live; epilogue/stage-2 remain half-split, LDS same).
//      -16 ds_read_b128/wave, wqk reads halved.
//  (2) softmax without max-subtraction (exact no-op for the ratio; |l|<~3
//      so exp is tame in f32). -16 ds_bpermute/wave, kills the serial
//      4-level max chain on the critical path.
__global__ void __launch_bounds__(256, 6) attn_kernel(
    const float* __restrict__ X,          // (16,128,1024,16) f32
    const float* __restrict__ bqk,        // (128) f32
    const float* __restrict__ bv,         // (128) f32
    const unsigned int* __restrict__ wqk, // 128x128 bf16 as 8192 words
    const unsigned int* __restrict__ wv,  // 128x128 bf16 as 8192 words
    float* __restrict__ out)              // (16,1024,128) f32
{
  __shared__ unsigned int sXt[64 * 66];   // Xt[j=n*16+k][c-pair], stride 66 words
  __shared__ unsigned int sPt[64 * 34];   // P^T half: [j][o-pair 0..31], stride 34
  __shared__ unsigned int sY[4 * 68];     // y_n[c-pair] bf16
  __shared__ float sa[4][16];
  __shared__ float sS[4];

  const int t    = threadIdx.x;
  const int lane = t & 63;
  const int w    = t >> 6;      // wave 0..3
  const int nn   = lane & 15;
  const int quad = lane >> 4;

  const int blk = blockIdx.x;
  const int b   = blk >> 8;
  const int n0  = (blk & 255) << 2;

  // ---- Stage A: coalesced float4 + in-register 4x4 quad transpose -> sXt ----
  {
    const int j4 = nn;
    const int q  = quad;
    const float* Xg = X + (size_t)b * (128 * 1024 * 16) + (size_t)n0 * 16;
    #pragma unroll
    for (int it = 0; it < 8; ++it) {
      const int cbase = it * 16 + w * 4;      // multiple of 4
      const int c = cbase + q;
      float4 V = *reinterpret_cast<const float4*>(Xg + (size_t)c * 16384 + j4 * 4);
      {
        const bool Q0 = (q >> 1) == 0;
        float a  = Q0 ? V.z : V.x;
        float bb = Q0 ? V.w : V.y;
        a  = __shfl_xor(a, 32);
        bb = __shfl_xor(bb, 32);
        if (Q0) { V.z = a; V.w = bb; } else { V.x = a; V.y = bb; }
      }
      {
        const bool q0 = (q & 1) == 0;
        float a  = q0 ? V.y : V.x;
        float bb = q0 ? V.w : V.z;
        a  = __shfl_xor(a, 16);
        bb = __shfl_xor(bb, 16);
        if (q0) { V.y = a; V.w = bb; } else { V.x = a; V.z = bb; }
      }
      const int j = 4 * j4 + q;
      uint2 pk;
      pk.x = pack_bf2(V.x, V.y);
      pk.y = pack_bf2(V.z, V.w);
      *reinterpret_cast<uint2*>(&sXt[j * 66 + (cbase >> 1)]) = pk;
    }
  }
  __syncthreads();

  // ---- Stage 1 unified: both o-halves with single bf loads ----
  // wave w owns o-tiles Ob+32h (half h); same colbase both halves.
  const int Ob      = (w < 2) ? (16 * w) : (64 + 16 * (w - 2));
  const int colbase = (w < 2) ? (8 * w)  : (16 + 8 * (w - 2));
  f32x4 acc[2][4];
  #pragma unroll
  for (int h = 0; h < 2; ++h) {
    const float4 bq = *reinterpret_cast<const float4*>(bqk + Ob + 32 * h + quad * 4);
    #pragma unroll
    for (int tt = 0; tt < 4; ++tt) {
      acc[h][tt][0] = bq.x; acc[h][tt][1] = bq.y;
      acc[h][tt][2] = bq.z; acc[h][tt][3] = bq.w;
    }
  }
  #pragma unroll
  for (int ks = 0; ks < 4; ++ks) {
    FragU bf[4];
    #pragma unroll
    for (int tt = 0; tt < 4; ++tt)
      bf[tt].u = *reinterpret_cast<const uint4*>(&sXt[(tt * 16 + nn) * 66 + ks * 16 + quad * 4]);
    #pragma unroll
    for (int h = 0; h < 2; ++h) {
      FragU af;
      af.u = *reinterpret_cast<const uint4*>(wqk + (Ob + 32 * h + nn) * 64 + ks * 16 + quad * 4);
      #pragma unroll
      for (int tt = 0; tt < 4; ++tt)
        acc[h][tt] = __builtin_amdgcn_mfma_f32_16x16x32_bf16(af.s, bf[tt].s, acc[h][tt], 0, 0, 0);
    }
  }

  // ---- Half-split exchange + E accumulation (proven R6 layout) ----
  f32x4 e; e[0] = 0.f; e[1] = 0.f; e[2] = 0.f; e[3] = 0.f;
  #pragma unroll
  for (int h = 0; h < 2; ++h) {
    // Epilogue: Pt[j][colbase + quad*2 + {0,1}] (pair parity trick)
    #pragma unroll
    for (int tt = 0; tt < 4; ++tt) {
      const int j = tt * 16 + nn;
      const unsigned int pw0 = pack_bf2(acc[h][tt][0], acc[h][tt][1]);
      const unsigned int pw1 = pack_bf2(acc[h][tt][2], acc[h][tt][3]);
      #pragma unroll
      for (int s = 0; s < 2; ++s) {
        const int rp = (nn + s) & 1;
        sPt[j * 34 + colbase + quad * 2 + rp] = rp ? pw1 : pw0;
      }
    }
    __syncthreads();   // Pt half complete -> all waves may read

    // Stage 2 half h: E += Q_h^T K_h (wave w -> n=w)
    {
      const int row = (w * 16 + nn) * 34;
      FragU qf, kf;
      const uint2 qlo = *reinterpret_cast<const uint2*>(&sPt[row + quad * 4]);
      const uint2 qhi = *reinterpret_cast<const uint2*>(&sPt[row + quad * 4 + 2]);
      const uint2 klo = *reinterpret_cast<const uint2*>(&sPt[row + 16 + quad * 4]);
      const uint2 khi = *reinterpret_cast<const uint2*>(&sPt[row + 16 + quad * 4 + 2]);
      qf.u.x = qlo.x; qf.u.y = qlo.y; qf.u.z = qhi.x; qf.u.w = qhi.y;
      kf.u.x = klo.x; kf.u.y = klo.y; kf.u.z = khi.x; kf.u.w = khi.y;
      e = __builtin_amdgcn_mfma_f32_16x16x32_bf16(qf.s, kf.s, e, 0, 0, 0);
    }
    if (h == 0) __syncthreads();   // protect Pt from half-1 overwrite
  }

  // ---- softmax over k (cols = nn), rows q = quad*4 + rr — NO max-sub ----
  // exp cancels exactly in p/sum; |l| <~3 here so f32 exp/sum are tame.
  {
    float p[4], sm[4];
    #pragma unroll
    for (int rr = 0; rr < 4; ++rr) {
      const float pe = __expf(e[rr] * 0.125f);         // /sqrt(64)
      float ss = pe;
      ss += __shfl_xor(ss, 1);
      ss += __shfl_xor(ss, 2);
      ss += __shfl_xor(ss, 4);
      ss += __shfl_xor(ss, 8);
      p[rr] = pe; sm[rr] = ss;
    }
    if (nn == 0) {
      #pragma unroll
      for (int rr = 0; rr < 4; ++rr) sa[w][quad * 4 + rr] = p[rr] / sm[rr];
    }
  }

  // ---- Stage Y: y_n = X_n a_n -> sY row w (bf16); S_n (wave-local) ----
  {
    float a[16];
    float S = 0.f;
    #pragma unroll
    for (int k = 0; k < 16; ++k) { a[k] = sa[w][k]; S += a[k]; }
    float y0 = 0.f, y1 = 0.f;
    #pragma unroll
    for (int k = 0; k < 16; ++k) {
      const unsigned int xw = sXt[(w * 16 + k) * 66 + lane];   // stride-1
      y0 += a[k] * bflo(xw);
      y1 += a[k] * bfhi(xw);
    }
    sY[w * 68 + lane] = pack_bf2(y0, y1);
    if (lane == 0) sS[w] = S;
  }
  __syncthreads();   // sY/sS cross-wave -> stage 3

  // ---- Stage 3: Out = Wv @ Y + bv * S ----
  {
    #pragma unroll
    for (int i = 0; i < 2; ++i) {
      const int ct = w * 2 + i;   // c-out tile, 8 tiles over 4 waves
      f32x4 z; z[0] = 0.f; z[1] = 0.f; z[2] = 0.f; z[3] = 0.f;
      #pragma unroll
      for (int ks = 0; ks < 4; ++ks) {
        FragU av, by;
        av.u = *reinterpret_cast<const uint4*>(wv + (ct * 16 + nn) * 64 + ks * 16 + quad * 4);
        uint4 tmp; tmp.x = 0u; tmp.y = 0u; tmp.z = 0u; tmp.w = 0u;
        if (nn < 4) tmp = *reinterpret_cast<const uint4*>(&sY[nn * 68 + ks * 16 + quad * 4]);
        by.u = tmp;
        z = __builtin_amdgcn_mfma_f32_16x16x32_bf16(av.s, by.s, z, 0, 0, 0);
      }
      if (nn < 4) {
        const float4 bvv = *reinterpret_cast<const float4*>(bv + ct * 16 + quad * 4);
        const float S = sS[nn];
        float4 o4;
        o4.x = z[0] + bvv.x * S;
        o4.y = z[1] + bvv.y * S;
        o4.z = z[2] + bvv.z * S;
        o4.w = z[3] + bvv.w * S;
        *reinterpret_cast<float4*>(out + (size_t)(b * 1024 + n0 + nn) * 128 + ct * 16 + quad * 4) = o4;
      }
    }
  }
}

extern "C" void kernel_launch(void* const* d_in, const int* in_sizes, int n_in,
                              void* d_out, int out_size, void* d_ws, size_t ws_size,
                              hipStream_t stream) {
  (void)in_sizes; (void)n_in; (void)out_size; (void)ws_size;
  const float* X   = (const float*)d_in[0];
  const float* Wqk = (const float*)d_in[1];
  const float* bqk = (const float*)d_in[2];
  const float* Wv  = (const float*)d_in[3];
  const float* bv  = (const float*)d_in[4];
  // d_in[5] = qk_dim (=64), compile-time constant here.

  uint16_t* wsqk = (uint16_t*)d_ws;           // 32 KB
  uint16_t* wsv  = wsqk + 16384;              // 32 KB

  prep_weights<<<128, 256, 0, stream>>>(Wqk, Wv, wsqk, wsv);
  attn_kernel<<<4096, 256, 0, stream>>>(X, bqk, bv,
                                        (const unsigned int*)wsqk,
                                        (const unsigned int*)wsv,
                                        (float*)d_out);
}